// Round 7
// baseline (6191.705 us; speedup 1.0000x reference)
//
#include <hip/hip_runtime.h>
#include <math.h>

// ---------------- problem constants ----------------
namespace {
constexpr int NB = 4;
constexpr int SEQ = 128;
constexpr int TH_ = 120;
constexpr int NSTEP = 8;
constexpr int DMODEL = 512;
constexpr int NHEAD = 8;
constexpr int DHEAD = 64;
constexpr int DFFN = 2048;
constexpr int DIN = 32;
constexpr int MROWS = NB*SEQ;   // 512 flattened rows
constexpr float SCALE_EMB = 22.627416997969522f; // sqrt(512)
constexpr float LN_EPS = 1e-5f;
constexpr float NEGF = -3.4028234663852886e38f;  // jnp.finfo(f32).min
constexpr float PE_C = -0.017988946039015984f;   // -ln(10000)/512
}

using short8 = __attribute__((ext_vector_type(8))) short;
using f32x4  = __attribute__((ext_vector_type(4))) float;

// ---------------- device helpers ----------------
__device__ __forceinline__ float wave_sum(float v){
#pragma unroll
  for(int off=32;off;off>>=1) v += __shfl_xor(v,off,64);
  return v;
}
__device__ __forceinline__ float blk_sum(float v, float* scr){
  v = wave_sum(v);
  __syncthreads();
  if((threadIdx.x&63)==0) scr[threadIdx.x>>6]=v;
  __syncthreads();
  return scr[0]+scr[1]+scr[2]+scr[3];
}
__device__ __forceinline__ float gelu_t(float x){
  float t = 0.7978845608028654f*(x + 0.044715f*x*x*x);
  return 0.5f*x*(1.0f + tanhf(t));
}
__device__ __forceinline__ float pe_val(int t, int d){
  float div = expf((float)(d & ~1) * PE_C);
  float a = (float)t * div;
  return (d & 1) ? cosf(a) : sinf(a);
}
__device__ __forceinline__ unsigned short f2b(float f){
  union { float f; unsigned u; } c; c.f = f;
  unsigned u = c.u + 0x7FFFu + ((c.u>>16)&1u);
  return (unsigned short)(u>>16);
}
__device__ __forceinline__ short8 pack8(const float* f){
  short8 s;
#pragma unroll
  for(int i=0;i<8;i++) s[i] = (short)f2b(f[i]);
  return s;
}

// ---------------- one-time: convert all weights to bf16 ----------------
__global__ __launch_bounds__(256) void conv_w(const float* __restrict__ Wq,
                                              const float* __restrict__ Wk,
                                              const float* __restrict__ Wv,
                                              const float* __restrict__ Wo,
                                              const float* __restrict__ W1,
                                              const float* __restrict__ W2,
                                              unsigned short* __restrict__ dst){
  size_t base = ((size_t)blockIdx.x*256 + threadIdx.x)*8;
  if(base >= 12582912u) return;
  const float* src; size_t off;
  if(base < 1048576u){ src=Wq; off=base; }
  else if(base < 2097152u){ src=Wk; off=base-1048576u; }
  else if(base < 3145728u){ src=Wv; off=base-2097152u; }
  else if(base < 4194304u){ src=Wo; off=base-3145728u; }
  else if(base < 8388608u){ src=W1; off=base-4194304u; }
  else { src=W2; off=base-8388608u; }
  float4 a = *(const float4*)(src+off);
  float4 b = *(const float4*)(src+off+4);
  float f[8] = {a.x,a.y,a.z,a.w,b.x,b.y,b.z,b.w};
  *(short8*)(dst + base) = pack8(f);
}

// ---------------- h0 init (fp32 + bf16) ----------------
__global__ __launch_bounds__(256) void init_h0(const float* __restrict__ hist,
                                               const float* __restrict__ W_emb,
                                               const float* __restrict__ b_emb,
                                               float* __restrict__ h0,
                                               unsigned short* __restrict__ h0b){
  int bt = blockIdx.x;
  int b = bt >> 7, t = bt & 127;
  __shared__ float x[DIN];
  if(threadIdx.x < DIN)
    x[threadIdx.x] = (t < TH_) ? hist[((size_t)b*TH_ + t)*DIN + threadIdx.x] : 0.f;
  __syncthreads();
  for(int d = threadIdx.x; d < DMODEL; d += 256){
    float s = 0.f;
#pragma unroll 8
    for(int i=0;i<DIN;i++) s += W_emb[d*DIN+i]*x[i];
    float v = SCALE_EMB*(s + b_emb[d]) + pe_val(t,d);
    h0[(size_t)bt*DMODEL + d] = v;
    h0b[(size_t)bt*DMODEL + d] = f2b(v);
  }
}

// ---------------- M1 / cb1 / cur_x init (parallelized: 1 thread per (j,i)) -----------
__global__ __launch_bounds__(256) void init_misc(const float* __restrict__ Wr1,
                                                 const float* __restrict__ W_emb,
                                                 const float* __restrict__ b_emb,
                                                 const float* __restrict__ br1,
                                                 const float* __restrict__ hist,
                                                 float* __restrict__ M1,
                                                 float* __restrict__ cb1,
                                                 float* __restrict__ cur_x){
  __shared__ float rows8[8][DMODEL];
  int tid = threadIdx.x;
  int j0 = blockIdx.x*8;
  for(int idx=tid; idx<8*DMODEL; idx+=256)
    rows8[idx>>9][idx&511] = Wr1[(size_t)(j0+(idx>>9))*1024 + (idx&511)];
  __syncthreads();
  int jj = tid>>5, i = tid&31;
  int j = j0+jj;
  float s = 0.f;
#pragma unroll 8
  for(int k=0;k<DMODEL;k++) s += rows8[jj][k]*W_emb[k*DIN+i];
  M1[j*DIN+i] = SCALE_EMB*s;
  if(i==0){
    float sb = 0.f;
#pragma unroll 8
    for(int k=0;k<DMODEL;k++) sb += rows8[jj][k]*b_emb[k];
    cb1[j] = br1[j] + SCALE_EMB*sb;
  }
  if(blockIdx.x==0 && tid<NB*DIN){
    int b = tid>>5, ii = tid&31;
    cur_x[b*DIN+ii] = hist[((size_t)b*TH_ + (TH_-1))*DIN + ii];
  }
}

// ---------------- bf16 MFMA GEMM tile 64x128, 4 waves, DIRECT-FRAG (no LDS tiles) ----
// LNM: 0 = plain bf16 A; 1 = A operand is LN(lnx)*g+b built per-fragment in regs;
//      2 = plain bf16 A + epilogue residual LN(lnx)*g+b.
// Fragment addresses equal the old LDS-tile mapping, read straight from global:
//   af[rt][kf] = A16[(m0+rt*16+fr)*Ka + k0+kf*32+fq]   (8 bf16, 16B)
//   bf[ct][kf] = Wsrc[(nrow0+32w+ct*16+fr)*Ka + k0+kf*32+fq]
// No barriers in the K-loop; 2-deep named ping-pong lets the compiler pipeline.
template<int LNM>
__global__ __launch_bounds__(256,1) void gemm_k(
    const unsigned short* __restrict__ A16, int Ka,
    const unsigned short* __restrict__ Wa,
    const unsigned short* __restrict__ Wb,
    const unsigned short* __restrict__ Wc,
    const float* __restrict__ bias, const float* __restrict__ resid,
    const float* __restrict__ lnx, const float* __restrict__ lng,
    const float* __restrict__ lnbta,
    float* __restrict__ Cf, unsigned short* __restrict__ Cb,
    int c_rs, int c_mode, int act)
{
  __shared__ float Smu[64], Srs[64];
  __shared__ float Sgs[DMODEL], Scs[DMODEL];

  int bx = blockIdx.x, by = blockIdx.y;
  int n0 = bx*128;
  int m0 = by*64;
  int tid = threadIdx.x, w = tid>>6, ln = tid&63;
  int fr = ln&15, fq = (ln>>4)*8;

  const unsigned short* Wsrc; int nrow0;
  if(c_mode==2){ int which = n0>>9; Wsrc = (which==0?Wa:(which==1?Wb:Wc)); nrow0 = n0&511; }
  else { Wsrc = Wa; nrow0 = n0; }

  // ---- LN row-stats prologue (exact wave-per-row reduction -> bit-identical mu/rs) ----
  if constexpr(LNM != 0){
    float4 xr[16][2];
#pragma unroll
    for(int rr=0;rr<16;rr++){
      const float* xp = lnx + (size_t)(m0 + w*16 + rr)*DMODEL + ln*8;
      xr[rr][0] = *(const float4*)xp;
      xr[rr][1] = *(const float4*)(xp+4);
    }
    if constexpr(LNM==1){
      for(int k=tid;k<DMODEL;k+=256){ Sgs[k]=lng[k]; Scs[k]=lnbta[k]; }
    }
#pragma unroll
    for(int rr=0;rr<16;rr++){
      float f[8] = {xr[rr][0].x,xr[rr][0].y,xr[rr][0].z,xr[rr][0].w,
                    xr[rr][1].x,xr[rr][1].y,xr[rr][1].z,xr[rr][1].w};
      float s = 0.f;
#pragma unroll
      for(int i=0;i<8;i++) s += f[i];
      s = wave_sum(s);
      float mu = s*(1.f/DMODEL);
      float v2 = 0.f;
#pragma unroll
      for(int i=0;i<8;i++){ float d0=f[i]-mu; v2 += d0*d0; }
      v2 = wave_sum(v2);
      float rsv = rsqrtf(v2*(1.f/DMODEL) + LN_EPS);
      if(ln==0){ Smu[w*16+rr]=mu; Srs[w*16+rr]=rsv; }
    }
    __syncthreads();
  }

  float amu[4], ars[4];
  if constexpr(LNM==1){
#pragma unroll
    for(int rt=0;rt<4;rt++){ amu[rt]=Smu[rt*16+fr]; ars[rt]=Srs[rt*16+fr]; }
  }

  f32x4 acc[4][2];
#pragma unroll
  for(int i=0;i<4;i++)
#pragma unroll
    for(int j=0;j<2;j++) acc[i][j] = (f32x4){0.f,0.f,0.f,0.f};

  const unsigned short* aB = A16 ? (A16 + (size_t)(m0+fr)*Ka + fq) : (const unsigned short*)0;
  const float* aF = (LNM==1) ? (lnx + (size_t)(m0+fr)*DMODEL + fq) : (const float*)0;
  const unsigned short* bB = Wsrc + (size_t)(nrow0 + 32*w + fr)*Ka + fq;
  const int niter = Ka >> 6;

  // named ping-pong buffers (static indexing only)
  short8 A0[4][2], A1[4][2];        // LNM != 1
  float4 F0[4][2][2], F1[4][2][2];  // LNM == 1
  short8 B0[2][2], B1[2][2];

  auto LB0 = [&](int k0){
#pragma unroll
    for(int ct=0;ct<2;ct++)
#pragma unroll
      for(int kf=0;kf<2;kf++)
        B0[ct][kf] = *(const short8*)(bB + (size_t)ct*16*Ka + k0 + kf*32);
  };
  auto LB1 = [&](int k0){
#pragma unroll
    for(int ct=0;ct<2;ct++)
#pragma unroll
      for(int kf=0;kf<2;kf++)
        B1[ct][kf] = *(const short8*)(bB + (size_t)ct*16*Ka + k0 + kf*32);
  };
  auto LA0 = [&](int k0){
    if constexpr(LNM==1){
#pragma unroll
      for(int rt=0;rt<4;rt++)
#pragma unroll
        for(int kf=0;kf<2;kf++){
          const float* p = aF + (size_t)rt*16*DMODEL + k0 + kf*32;
          F0[rt][kf][0] = *(const float4*)p;
          F0[rt][kf][1] = *(const float4*)(p+4);
        }
    } else {
#pragma unroll
      for(int rt=0;rt<4;rt++)
#pragma unroll
        for(int kf=0;kf<2;kf++)
          A0[rt][kf] = *(const short8*)(aB + (size_t)rt*16*Ka + k0 + kf*32);
    }
  };
  auto LA1 = [&](int k0){
    if constexpr(LNM==1){
#pragma unroll
      for(int rt=0;rt<4;rt++)
#pragma unroll
        for(int kf=0;kf<2;kf++){
          const float* p = aF + (size_t)rt*16*DMODEL + k0 + kf*32;
          F1[rt][kf][0] = *(const float4*)p;
          F1[rt][kf][1] = *(const float4*)(p+4);
        }
    } else {
#pragma unroll
      for(int rt=0;rt<4;rt++)
#pragma unroll
        for(int kf=0;kf<2;kf++)
          A1[rt][kf] = *(const short8*)(aB + (size_t)rt*16*Ka + k0 + kf*32);
    }
  };
  auto CMP = [&](short8 (&af)[4][2], short8 (&bf)[2][2]){
#pragma unroll
    for(int kf=0;kf<2;kf++)
#pragma unroll
      for(int rt=0;rt<4;rt++)
#pragma unroll
        for(int ct=0;ct<2;ct++)
          acc[rt][ct] = __builtin_amdgcn_mfma_f32_16x16x32_bf16(af[rt][kf], bf[ct][kf], acc[rt][ct], 0, 0, 0);
  };
  auto CMPF = [&](float4 (&fa)[4][2][2], short8 (&bf)[2][2], int k0){
    short8 af[4][2];
#pragma unroll
    for(int kf=0;kf<2;kf++){
      int c0 = k0 + kf*32 + fq;
#pragma unroll
      for(int rt=0;rt<4;rt++){
        float o[8];
        float4 lo = fa[rt][kf][0], hi = fa[rt][kf][1];
        float x[8] = {lo.x,lo.y,lo.z,lo.w, hi.x,hi.y,hi.z,hi.w};
#pragma unroll
        for(int i=0;i<8;i++) o[i] = (x[i]-amu[rt])*ars[rt]*Sgs[c0+i] + Scs[c0+i];
        af[rt][kf] = pack8(o);
      }
    }
#pragma unroll
    for(int kf=0;kf<2;kf++)
#pragma unroll
      for(int rt=0;rt<4;rt++)
#pragma unroll
        for(int ct=0;ct<2;ct++)
          acc[rt][ct] = __builtin_amdgcn_mfma_f32_16x16x32_bf16(af[rt][kf], bf[ct][kf], acc[rt][ct], 0, 0, 0);
  };

  LA0(0); LB0(0);
#pragma unroll 2
  for(int i=0;i<niter;i+=2){
    int k1 = (i+1)<<6;
    LA1(k1); LB1(k1);
    if constexpr(LNM==1) CMPF(F0, B0, i<<6); else CMP(A0, B0);
    if(i+2<niter){ int k2=(i+2)<<6; LA0(k2); LB0(k2); }
    if constexpr(LNM==1) CMPF(F1, B1, k1); else CMP(A1, B1);
  }

  // ---- epilogue: batch residual loads, then compute + store ----
  float rv[4][2][4];
  const float* rsrc = (LNM==2) ? lnx : resid;
  if(rsrc){
#pragma unroll
    for(int rt=0;rt<4;rt++)
#pragma unroll
      for(int ct=0;ct<2;ct++){
        int n = n0 + 32*w + ct*16 + fr;
        int row0 = m0 + rt*16 + (ln>>4)*4;
        const float* p = rsrc + (size_t)row0*DMODEL + n;
#pragma unroll
        for(int r=0;r<4;r++) rv[rt][ct][r] = p[(size_t)r*DMODEL];
      }
  }

#pragma unroll
  for(int rt=0;rt<4;rt++){
#pragma unroll
    for(int ct=0;ct<2;ct++){
      int n = n0 + 32*w + ct*16 + fr;
      int ri0 = rt*16 + (ln>>4)*4;
      int row0 = m0 + ri0;
#pragma unroll
      for(int r=0;r<4;r++){
        int ri = ri0 + r;
        int row = row0 + r;
        float v = acc[rt][ct][r];
        if(bias)  v += bias[n];
        if constexpr(LNM==2){
          v += (rv[rt][ct][r] - Smu[ri])*Srs[ri]*lng[n] + lnbta[n];
        } else {
          if(rsrc) v += rv[rt][ct][r];
        }
        if(act==1) v = gelu_t(v);
        if(c_mode==0)      Cf[(size_t)row*c_rs + n] = v;
        else if(c_mode==1) Cb[(size_t)row*c_rs + n] = f2b(v);
        else {
          int which = n>>9, rem = n&511;
          int b = row>>7, t = row&127;
          Cf[(size_t)which*(MROWS*DMODEL) +
             ((size_t)(b*NHEAD + (rem>>6))*SEQ + t)*DHEAD + (rem&63)] = v;
        }
      }
    }
  }
}

// ---------------- fused attention per (b,h); full 128 rows; writes bf16 ---------------
__global__ __launch_bounds__(256) void attn_k(const float* __restrict__ qb,
                                              const float* __restrict__ kb,
                                              const float* __restrict__ vb,
                                              unsigned short* __restrict__ attb){
  int b = blockIdx.z, h = blockIdx.y;
  int r0 = blockIdx.x*32;
  const float* Kh = kb + (size_t)(b*NHEAD+h)*SEQ*DHEAD;
  const float* Vh = vb + (size_t)(b*NHEAD+h)*SEQ*DHEAD;
  const float* Qh = qb + (size_t)(b*NHEAD+h)*SEQ*DHEAD;
  __shared__ float kv[SEQ][DHEAD];
  __shared__ float wsm[32][132];
  __shared__ float qs[32][68];
  int tid = threadIdx.x;
  int kk = tid>>4, d4 = (tid&15)*4;

  { // K stage (xor-swizzled) + Q stage: batched float4 loads
    float4 t[8];
#pragma unroll
    for(int i=0;i<8;i++) t[i] = *(const float4*)(Kh + (size_t)(kk+16*i)*DHEAD + d4);
    float4 q0 = *(const float4*)(Qh + (size_t)(r0+kk)*DHEAD + d4);
    float4 q1 = *(const float4*)(Qh + (size_t)(r0+kk+16)*DHEAD + d4);
#pragma unroll
    for(int i=0;i<8;i++){ int k = kk+16*i; *(float4*)&kv[k][d4 ^ (k&60)] = t[i]; }
    *(float4*)&qs[kk   ][d4] = q0;
    *(float4*)&qs[kk+16][d4] = q1;
  }
  __syncthreads();

  { // logits: 2 rows x 8 keys per thread, float4 LDS reads
    int rp = tid>>4;
    int kg = tid&15;
    float acc[2][8];
#pragma unroll
    for(int i=0;i<2;i++)
#pragma unroll
      for(int kk2=0;kk2<8;kk2++) acc[i][kk2]=0.f;
#pragma unroll 4
    for(int dd=0;dd<16;dd++){
      float4 q0 = *(const float4*)&qs[2*rp][dd*4];
      float4 q1 = *(const float4*)&qs[2*rp+1][dd*4];
#pragma unroll
      for(int kk2=0;kk2<8;kk2++){
        int k = 8*kg + kk2;
        int off = (dd*4) ^ (k&60);
        float4 kv4 = *(const float4*)&kv[k][off];
        acc[0][kk2] += q0.x*kv4.x + q0.y*kv4.y + q0.z*kv4.z + q0.w*kv4.w;
        acc[1][kk2] += q1.x*kv4.x + q1.y*kv4.y + q1.z*kv4.z + q1.w*kv4.w;
      }
    }
#pragma unroll
    for(int i=0;i<2;i++){
      int t = r0 + 2*rp + i;
#pragma unroll
      for(int kk2=0;kk2<8;kk2++){
        int k = 8*kg + kk2;
        wsm[2*rp+i][k] = (k > t) ? acc[i][kk2]*0.125f : NEGF;
      }
    }
  }
  __syncthreads();

  { // softmax per row (all-masked row -> uniform 1/128, faithful to jnp)
    int l2 = tid&63, wv = tid>>6;
    for(int r=wv;r<32;r+=4){
      float l0 = wsm[r][l2], l1 = wsm[r][l2+64];
      float m = fmaxf(l0,l1);
#pragma unroll
      for(int off=32;off;off>>=1) m = fmaxf(m, __shfl_xor(m,off,64));
      float e0 = expf(l0-m), e1 = expf(l1-m);
      float s = e0+e1;
      s = wave_sum(s);
      float inv = 1.f/s;
      wsm[r][l2] = e0*inv; wsm[r][l2+64] = e1*inv;
    }
  }
  __syncthreads();

  { // V stage (overwrite kv, no swizzle): batched float4 loads
    float4 t[8];
#pragma unroll
    for(int i=0;i<8;i++) t[i] = *(const float4*)(Vh + (size_t)(kk+16*i)*DHEAD + d4);
#pragma unroll
    for(int i=0;i<8;i++) *(float4*)&kv[kk+16*i][d4] = t[i];
  }
  __syncthreads();

  { // out = w @ V, pack bf16
    int dq = (tid&15)*4, rg = tid>>4;
    for(int r=rg;r<32;r+=16){
      float4 acc2 = make_float4(0.f,0.f,0.f,0.f);
      for(int k=0;k<SEQ;k++){
        float w0 = wsm[r][k];
        float4 v = *(const float4*)&kv[k][dq];
        acc2.x += w0*v.x; acc2.y += w0*v.y; acc2.z += w0*v.z; acc2.w += w0*v.w;
      }
      int row = b*SEQ + r0 + r;
      unsigned short* op = attb + (size_t)row*DMODEL + h*DHEAD + dq;
      op[0]=f2b(acc2.x); op[1]=f2b(acc2.y); op[2]=f2b(acc2.z); op[3]=f2b(acc2.w);
    }
  }
}

// ---------------- ctx = LN2_3(r2[ptr-1]); ctxt = Wr1b@ctx + cb1 -----------------------
__global__ __launch_bounds__(256) void ctx_k(const float* __restrict__ r2,
                                             const float* __restrict__ g2,
                                             const float* __restrict__ b2,
                                             const float* __restrict__ Wr1,
                                             const float* __restrict__ cb1,
                                             float* __restrict__ ctxt, int ptr){
  int b = blockIdx.y; int j0 = blockIdx.x*128;
  __shared__ float raw[DMODEL], ctx[DMODEL], scr[4];
  int tid = threadIdx.x;
  const float* rp = r2 + (size_t)(b*SEQ + ptr-1)*DMODEL;
  for(int k=tid;k<DMODEL;k+=256) raw[k]=rp[k];
  __syncthreads();
  float s = 0.f;
  for(int k=tid;k<DMODEL;k+=256) s += raw[k];
  s = blk_sum(s, scr);
  float mu = s/(float)DMODEL;
  float v = 0.f;
  for(int k=tid;k<DMODEL;k+=256){ float d0 = raw[k]-mu; v += d0*d0; }
  v = blk_sum(v, scr);
  float rs = rsqrtf(v/(float)DMODEL + LN_EPS);
  for(int k=tid;k<DMODEL;k+=256) ctx[k] = (raw[k]-mu)*rs*g2[k] + b2[k];
  __syncthreads();
  int wv = tid>>6, l2 = tid&63;
  for(int jj=wv;jj<128;jj+=4){
    int j = j0+jj;
    const float* wp = Wr1 + (size_t)j*1024 + 512;
    float acc = 0.f;
#pragma unroll
    for(int q=0;q<8;q++){ int k = l2 + 64*q; acc += wp[k]*ctx[k]; }
    acc = wave_sum(acc);
    if(l2==0) ctxt[b*DFFN + j] = acc + cb1[j];
  }
}

// ---------------- fused refine (5 substeps) + finalize, one wg per batch --------------
__global__ __launch_bounds__(256) void refine_fin(const float* __restrict__ M1,
                                                  const float* __restrict__ ctxt,
                                                  const float* __restrict__ Wr2,
                                                  const float* __restrict__ br2,
                                                  float* __restrict__ cur_x,
                                                  const float* __restrict__ W_emb,
                                                  const float* __restrict__ b_emb,
                                                  float* __restrict__ out,
                                                  float* __restrict__ h0,
                                                  unsigned short* __restrict__ h0b,
                                                  int s, int ptr){
  int b = blockIdx.x, tid = threadIdx.x;
  __shared__ float cur[DIN], gs[DFFN], dscr[DIN];
  if(tid < DIN) cur[tid] = cur_x[b*DIN + tid];
  __syncthreads();
  for(int sub=0; sub<5; sub++){
    for(int jj=tid; jj<DFFN; jj+=256){
      float u = ctxt[b*DFFN + jj];
      const float* mp = M1 + (size_t)jj*DIN;
#pragma unroll
      for(int p=0;p<8;p++){
        float4 mv = *(const float4*)(mp + 4*p);
        u += mv.x*cur[4*p] + mv.y*cur[4*p+1] + mv.z*cur[4*p+2] + mv.w*cur[4*p+3];
      }
      gs[jj] = gelu_t(u);
    }
    __syncthreads();
    int w = tid>>6, l = tid&63;
#pragma unroll
    for(int q=0;q<8;q++){
      int i = w*8 + q;
      const float* wr = Wr2 + (size_t)i*DFFN;
      float a = 0.f;
#pragma unroll
      for(int p=0;p<8;p++){
        int j0 = p*256 + l*4;
        float4 wv = *(const float4*)(wr + j0);
        float4 gv = *(const float4*)&gs[j0];
        a += wv.x*gv.x + wv.y*gv.y + wv.z*gv.z + wv.w*gv.w;
      }
      a = wave_sum(a);
      if(l==0) dscr[i] = a;
    }
    __syncthreads();
    if(tid < DIN) cur[tid] += dscr[tid] + br2[tid];
    __syncthreads();
  }
  if(tid < DIN){
    out[(b*NSTEP + s)*DIN + tid] = cur[tid];
    cur_x[b*DIN + tid] = cur[tid];
  }
  __syncthreads();
  for(int d=tid; d<DMODEL; d+=256){
    float s2 = 0.f;
#pragma unroll 8
    for(int i=0;i<DIN;i++) s2 += W_emb[d*DIN+i]*cur[i];
    float v = SCALE_EMB*(s2 + b_emb[d]) + pe_val(ptr, d);
    size_t idx = (size_t)(b*SEQ + ptr)*DMODEL + d;
    h0[idx] = v;
    h0b[idx] = f2b(v);
  }
}

// ---------------- host ----------------
extern "C" void kernel_launch(void* const* d_in, const int* in_sizes, int n_in,
                              void* d_out, int out_size, void* d_ws, size_t ws_size,
                              hipStream_t stream) {
  (void)in_sizes; (void)n_in; (void)out_size; (void)ws_size;
  const float* hist = (const float*)d_in[0];
  const float* W_emb= (const float*)d_in[2];
  const float* b_emb= (const float*)d_in[3];
  const float* Wq   = (const float*)d_in[4];
  const float* Wk   = (const float*)d_in[5];
  const float* Wv   = (const float*)d_in[6];
  const float* Wo   = (const float*)d_in[7];
  const float* ln1g = (const float*)d_in[8];
  const float* ln1b = (const float*)d_in[9];
  const float* W1   = (const float*)d_in[10];
  const float* b1   = (const float*)d_in[11];
  const float* W2   = (const float*)d_in[12];
  const float* b2v  = (const float*)d_in[13];
  const float* ln2g = (const float*)d_in[14];
  const float* ln2b = (const float*)d_in[15];
  const float* Wr1  = (const float*)d_in[16];
  const float* br1  = (const float*)d_in[17];
  const float* Wr2  = (const float*)d_in[18];
  const float* br2  = (const float*)d_in[19];
  float* out = (float*)d_out;
  float* ws  = (float*)d_ws;

  const size_t BTD = (size_t)MROWS*DMODEL;      // 262144 floats
  const size_t BTDH = BTD/2;                    // bf16 buffer in float units
  float* h0   = ws;
  unsigned short* h0b = (unsigned short*)(h0 + BTD);
  float* r2   = h0 + BTD + BTDH;
  float* hln  = r2 + BTD;                       // dead (layout compat)
  float* hp   = hln + BTD;                      // reused as r1 (pre-LN1 residual)
  float* qb   = hp + BTD + BTDH;
  float* kb   = qb + BTD;
  float* vb   = kb + BTD;
  unsigned short* attb = (unsigned short*)(vb + BTD);
  unsigned short* fbuf16 = (unsigned short*)qb;   // [512][2048] bf16 (over qb/kb, dead then)
  float* r1   = hp;
  unsigned short* W16 = (unsigned short*)(qb + 4*BTD);
  float* after_w = qb + 4*BTD + 6291456;
  float* M1   = after_w;
  float* cb1  = M1 + (size_t)DFFN*DIN;
  float* ctxt = cb1 + DFFN;
  float* cur_x= ctxt + NB*DFFN;

  unsigned short* Wq16 = W16;
  unsigned short* Wk16 = W16 + 1048576;
  unsigned short* Wv16 = W16 + 2097152;
  unsigned short* Wo16 = W16 + 3145728;
  unsigned short* W116 = W16 + 4194304;
  unsigned short* W216 = W16 + 8388608;

  conv_w<<<dim3(6144),dim3(256),0,stream>>>(Wq,Wk,Wv,Wo,W1,W2,W16);
  init_h0<<<dim3(MROWS),dim3(256),0,stream>>>(hist,W_emb,b_emb,h0,h0b);
  init_misc<<<dim3(256),dim3(256),0,stream>>>(Wr1,W_emb,b_emb,br1,hist,M1,cb1,cur_x);

  for(int s=0;s<NSTEP;s++){
    int ptr = TH_ + s;
    for(int l=0;l<4;l++){
      const float* g2p = ln2g + (l-1)*DMODEL;   // only valid when l>0
      const float* b2p = ln2b + (l-1)*DMODEL;
      const float* g1p = ln1g + l*DMODEL;
      const float* b1p = ln1b + l*DMODEL;

      // QKV (A = l==0 ? h0b : LN2(r2) fused); N=1536 scatter -> qb/kb/vb
      if(l==0)
        gemm_k<0><<<dim3(12,8),dim3(256),0,stream>>>(h0b, DMODEL,
            Wq16 + (size_t)l*262144, Wk16 + (size_t)l*262144, Wv16 + (size_t)l*262144,
            nullptr, nullptr, nullptr, nullptr, nullptr,
            qb, nullptr, 0, 2, 0);
      else
        gemm_k<1><<<dim3(12,8),dim3(256),0,stream>>>(nullptr, DMODEL,
            Wq16 + (size_t)l*262144, Wk16 + (size_t)l*262144, Wv16 + (size_t)l*262144,
            nullptr, nullptr, r2, g2p, b2p,
            qb, nullptr, 0, 2, 0);

      attn_k<<<dim3(4,NHEAD,NB),dim3(256),0,stream>>>(qb,kb,vb,attb);

      // Wo: att@Wo^T + (l==0 ? h0 : LN2(r2)) -> r1 fp32
      if(l==0)
        gemm_k<0><<<dim3(4,8),dim3(256),0,stream>>>(attb, DMODEL,
            Wo16 + (size_t)l*262144, nullptr, nullptr,
            nullptr, h0, nullptr, nullptr, nullptr,
            r1, nullptr, DMODEL, 0, 0);
      else
        gemm_k<2><<<dim3(4,8),dim3(256),0,stream>>>(attb, DMODEL,
            Wo16 + (size_t)l*262144, nullptr, nullptr,
            nullptr, nullptr, r2, g2p, b2p,
            r1, nullptr, DMODEL, 0, 0);

      // FF1: gelu(LN1(r1)@W1^T + b1) -> fbuf bf16
      gemm_k<1><<<dim3(16,8),dim3(256),0,stream>>>(nullptr, DMODEL,
          W116 + (size_t)l*1048576, nullptr, nullptr,
          b1 + l*DFFN, nullptr, r1, g1p, b1p,
          nullptr, fbuf16, DFFN, 1, 1);

      // FF2: fbuf@W2^T + b2 + LN1(r1) -> r2 fp32
      gemm_k<2><<<dim3(4,8),dim3(256),0,stream>>>(fbuf16, DFFN,
          W216 + (size_t)l*1048576, nullptr, nullptr,
          b2v + l*DMODEL, nullptr, r1, g1p, b1p,
          r2, nullptr, DMODEL, 0, 0);
    }

    ctx_k<<<dim3(16,NB),dim3(256),0,stream>>>(r2, ln2g + 3*DMODEL, ln2b + 3*DMODEL,
                                              Wr1, cb1, ctxt, ptr);
    refine_fin<<<dim3(NB),dim3(256),0,stream>>>(M1, ctxt, Wr2, br2, cur_x,
                                                W_emb, b_emb, out, h0, h0b, s, ptr);
  }
}

// Round 8
// 6043.777 us; speedup vs baseline: 1.0245x; 1.0245x over previous
//
#include <hip/hip_runtime.h>
#include <math.h>

// ---------------- problem constants ----------------
namespace {
constexpr int NB = 4;
constexpr int SEQ = 128;
constexpr int TH_ = 120;
constexpr int NSTEP = 8;
constexpr int DMODEL = 512;
constexpr int NHEAD = 8;
constexpr int DHEAD = 64;
constexpr int DFFN = 2048;
constexpr int DIN = 32;
constexpr int MROWS = NB*SEQ;   // 512 flattened rows
constexpr float SCALE_EMB = 22.627416997969522f; // sqrt(512)
constexpr float LN_EPS = 1e-5f;
constexpr float NEGF = -3.4028234663852886e38f;  // jnp.finfo(f32).min
constexpr float PE_C = -0.017988946039015984f;   // -ln(10000)/512
}

using short8 = __attribute__((ext_vector_type(8))) short;
using f32x4  = __attribute__((ext_vector_type(4))) float;

// ---------------- device helpers ----------------
__device__ __forceinline__ float wave_sum(float v){
#pragma unroll
  for(int off=32;off;off>>=1) v += __shfl_xor(v,off,64);
  return v;
}
__device__ __forceinline__ float blk_sum(float v, float* scr){
  v = wave_sum(v);
  __syncthreads();
  if((threadIdx.x&63)==0) scr[threadIdx.x>>6]=v;
  __syncthreads();
  return scr[0]+scr[1]+scr[2]+scr[3];
}
__device__ __forceinline__ float gelu_t(float x){
  float t = 0.7978845608028654f*(x + 0.044715f*x*x*x);
  return 0.5f*x*(1.0f + tanhf(t));
}
__device__ __forceinline__ float pe_val(int t, int d){
  float div = expf((float)(d & ~1) * PE_C);
  float a = (float)t * div;
  return (d & 1) ? cosf(a) : sinf(a);
}
__device__ __forceinline__ unsigned short f2b(float f){
  union { float f; unsigned u; } c; c.f = f;
  unsigned u = c.u + 0x7FFFu + ((c.u>>16)&1u);
  return (unsigned short)(u>>16);
}
__device__ __forceinline__ short8 pack8(const float* f){
  short8 s;
#pragma unroll
  for(int i=0;i<8;i++) s[i] = (short)f2b(f[i]);
  return s;
}

// ---------------- one-time: convert all weights to bf16 ----------------
__global__ __launch_bounds__(256) void conv_w(const float* __restrict__ Wq,
                                              const float* __restrict__ Wk,
                                              const float* __restrict__ Wv,
                                              const float* __restrict__ Wo,
                                              const float* __restrict__ W1,
                                              const float* __restrict__ W2,
                                              unsigned short* __restrict__ dst){
  size_t base = ((size_t)blockIdx.x*256 + threadIdx.x)*8;
  if(base >= 12582912u) return;
  const float* src; size_t off;
  if(base < 1048576u){ src=Wq; off=base; }
  else if(base < 2097152u){ src=Wk; off=base-1048576u; }
  else if(base < 3145728u){ src=Wv; off=base-2097152u; }
  else if(base < 4194304u){ src=Wo; off=base-3145728u; }
  else if(base < 8388608u){ src=W1; off=base-4194304u; }
  else { src=W2; off=base-8388608u; }
  float4 a = *(const float4*)(src+off);
  float4 b = *(const float4*)(src+off+4);
  float f[8] = {a.x,a.y,a.z,a.w,b.x,b.y,b.z,b.w};
  *(short8*)(dst + base) = pack8(f);
}

// ---------------- h0 init (fp32 + bf16) ----------------
__global__ __launch_bounds__(256) void init_h0(const float* __restrict__ hist,
                                               const float* __restrict__ W_emb,
                                               const float* __restrict__ b_emb,
                                               float* __restrict__ h0,
                                               unsigned short* __restrict__ h0b){
  int bt = blockIdx.x;
  int b = bt >> 7, t = bt & 127;
  __shared__ float x[DIN];
  if(threadIdx.x < DIN)
    x[threadIdx.x] = (t < TH_) ? hist[((size_t)b*TH_ + t)*DIN + threadIdx.x] : 0.f;
  __syncthreads();
  for(int d = threadIdx.x; d < DMODEL; d += 256){
    float s = 0.f;
#pragma unroll 8
    for(int i=0;i<DIN;i++) s += W_emb[d*DIN+i]*x[i];
    float v = SCALE_EMB*(s + b_emb[d]) + pe_val(t,d);
    h0[(size_t)bt*DMODEL + d] = v;
    h0b[(size_t)bt*DMODEL + d] = f2b(v);
  }
}

// ---------------- M1 / cb1 / cur_x init (parallel: 1 thread per (j,i)) ----------------
__global__ __launch_bounds__(256) void init_misc(const float* __restrict__ Wr1,
                                                 const float* __restrict__ W_emb,
                                                 const float* __restrict__ b_emb,
                                                 const float* __restrict__ br1,
                                                 const float* __restrict__ hist,
                                                 float* __restrict__ M1,
                                                 float* __restrict__ cb1,
                                                 float* __restrict__ cur_x){
  __shared__ float rows8[8][DMODEL];
  int tid = threadIdx.x;
  int j0 = blockIdx.x*8;
  for(int idx=tid; idx<8*DMODEL; idx+=256)
    rows8[idx>>9][idx&511] = Wr1[(size_t)(j0+(idx>>9))*1024 + (idx&511)];
  __syncthreads();
  int jj = tid>>5, i = tid&31;
  int j = j0+jj;
  float s = 0.f;
#pragma unroll 8
  for(int k=0;k<DMODEL;k++) s += rows8[jj][k]*W_emb[k*DIN+i];
  M1[j*DIN+i] = SCALE_EMB*s;
  if(i==0){
    float sb = 0.f;
#pragma unroll 8
    for(int k=0;k<DMODEL;k++) sb += rows8[jj][k]*b_emb[k];
    cb1[j] = br1[j] + SCALE_EMB*sb;
  }
  if(blockIdx.x==0 && tid<NB*DIN){
    int b = tid>>5, ii = tid&31;
    cur_x[b*DIN+ii] = hist[((size_t)b*TH_ + (TH_-1))*DIN + ii];
  }
}

// ---------------- plain bf16 MFMA GEMM, tile 64x128, 4 waves, LDS-staged ---------------
// (baseline-proven path: reg-prefetch of next K-chunk while MFMAs run)
// c_mode: 0 -> Cf fp32 (+bias,+resid,+act); 1 -> Cb bf16 (+bias,+act);
//         2 -> fused QKV scatter fp32 (qb|kb|vb by n>>9), [b][h][t][64]
__global__ __launch_bounds__(256) void gemm_k(
    const unsigned short* __restrict__ A16, int Ka,
    const unsigned short* __restrict__ Wa,
    const unsigned short* __restrict__ Wb,
    const unsigned short* __restrict__ Wc,
    const float* __restrict__ bias, const float* __restrict__ resid,
    float* __restrict__ Cf, unsigned short* __restrict__ Cb,
    int c_rs, int c_mode, int act)
{
  __shared__ __align__(16) unsigned short As[64][72];
  __shared__ __align__(16) unsigned short Bs[128][72];

  int n0 = blockIdx.x*128;
  int m0 = blockIdx.y*64;
  int tid = threadIdx.x, w = tid>>6, ln = tid&63;

  const unsigned short* Wsrc; int nrow0;
  if(c_mode==2){ int which = n0>>9; Wsrc = (which==0?Wa:(which==1?Wb:Wc)); nrow0 = n0&511; }
  else { Wsrc = Wa; nrow0 = n0; }

  f32x4 acc[4][2];
#pragma unroll
  for(int i=0;i<4;i++)
#pragma unroll
    for(int j=0;j<2;j++) acc[i][j] = (f32x4){0.f,0.f,0.f,0.f};

  int fr = ln&15, fq = (ln>>4)*8;
  int arow = tid>>2, akq = (tid&3)*16;
  int brow = tid>>1, bkq = (tid&1)*32;

  short8 a0, a1, b0, b1, b2, b3;
  auto LOAD = [&](int k0){
    const unsigned short* ap = A16 + (size_t)(m0+arow)*Ka + k0 + akq;
    a0 = *(const short8*)ap;
    a1 = *(const short8*)(ap+8);
    const unsigned short* bp = Wsrc + (size_t)(nrow0+brow)*Ka + k0 + bkq;
    b0 = *(const short8*)bp;
    b1 = *(const short8*)(bp+8);
    b2 = *(const short8*)(bp+16);
    b3 = *(const short8*)(bp+24);
  };

  LOAD(0);
  for(int k0=0;k0<Ka;k0+=64){
    *(short8*)&As[arow][akq]   = a0;
    *(short8*)&As[arow][akq+8] = a1;
    *(short8*)&Bs[brow][bkq]    = b0;
    *(short8*)&Bs[brow][bkq+8]  = b1;
    *(short8*)&Bs[brow][bkq+16] = b2;
    *(short8*)&Bs[brow][bkq+24] = b3;
    __syncthreads();
    if(k0+64 < Ka) LOAD(k0+64);
    short8 af[4][2], bf[2][2];
#pragma unroll
    for(int kf=0;kf<2;kf++){
#pragma unroll
      for(int rt=0;rt<4;rt++) af[rt][kf] = *(const short8*)&As[rt*16 + fr][kf*32 + fq];
#pragma unroll
      for(int ct=0;ct<2;ct++) bf[ct][kf] = *(const short8*)&Bs[32*w + ct*16 + fr][kf*32 + fq];
    }
#pragma unroll
    for(int kf=0;kf<2;kf++)
#pragma unroll
      for(int rt=0;rt<4;rt++)
#pragma unroll
        for(int ct=0;ct<2;ct++)
          acc[rt][ct] = __builtin_amdgcn_mfma_f32_16x16x32_bf16(af[rt][kf], bf[ct][kf], acc[rt][ct], 0, 0, 0);
    __syncthreads();
  }

#pragma unroll
  for(int rt=0;rt<4;rt++){
#pragma unroll
    for(int ct=0;ct<2;ct++){
      int n = n0 + 32*w + ct*16 + fr;
#pragma unroll
      for(int r=0;r<4;r++){
        int row = m0 + rt*16 + (ln>>4)*4 + r;
        float v = acc[rt][ct][r];
        if(bias)  v += bias[n];
        if(resid) v += resid[(size_t)row*DMODEL + n];
        if(act==1) v = gelu_t(v);
        if(c_mode==0)      Cf[(size_t)row*c_rs + n] = v;
        else if(c_mode==1) Cb[(size_t)row*c_rs + n] = f2b(v);
        else {
          int which = n>>9, rem = n&511;
          int b = row>>7, t = row&127;
          Cf[(size_t)which*(MROWS*DMODEL) +
             ((size_t)(b*NHEAD + (rem>>6))*SEQ + t)*DHEAD + (rem&63)] = v;
        }
      }
    }
  }
}

// ---------------- full-row GEMM + fused LayerNorm epilogue -----------------------------
// Tile: 32 rows x 512 cols (ALL cols -> in-block row stats). Grid = 16 blocks.
// Y = LN(A@W^T + bias + resid) * g + bta ; writes fp32 Yf and bf16 Yb.
__global__ __launch_bounds__(256,1) void gemm_row(
    const unsigned short* __restrict__ A16, int Ka,
    const unsigned short* __restrict__ W,      // [512][Ka] bf16
    const float* __restrict__ bias,            // per-col or nullptr
    const float* __restrict__ resid,           // [512][512] fp32
    const float* __restrict__ g, const float* __restrict__ bta,
    float* __restrict__ Yf, unsigned short* __restrict__ Yb)
{
  __shared__ __align__(16) unsigned short As[32][76];
  __shared__ __align__(16) unsigned short Bs[512][76];
  __shared__ float Ssum[32][4];
  __shared__ float Smu[32], Srs[32];

  int m0 = blockIdx.x*32;
  int tid = threadIdx.x, w = tid>>6, ln = tid&63;
  int fr = ln&15, fq = (ln>>4)*8;

  f32x4 acc[2][8];
#pragma unroll
  for(int i=0;i<2;i++)
#pragma unroll
    for(int j=0;j<8;j++) acc[i][j] = (f32x4){0.f,0.f,0.f,0.f};

  // staging indices: A 32x64 -> 8 shorts/thread; B 512x64 -> 2 rows x 64 shorts/thread
  int arow = tid>>3, aoff = (tid&7)*8;
  int brow = tid*2;

  short8 aR;
  short8 bR[16];
  auto LOAD = [&](int k0){
    aR = *(const short8*)(A16 + (size_t)(m0+arow)*Ka + k0 + aoff);
    const unsigned short* p0 = W + (size_t)brow*Ka + k0;
    const unsigned short* p1 = W + (size_t)(brow+1)*Ka + k0;
#pragma unroll
    for(int i=0;i<8;i++){
      bR[i]   = *(const short8*)(p0 + i*8);
      bR[8+i] = *(const short8*)(p1 + i*8);
    }
  };

  LOAD(0);
  for(int k0=0;k0<Ka;k0+=64){
    *(short8*)&As[arow][aoff] = aR;
#pragma unroll
    for(int i=0;i<8;i++){
      *(short8*)&Bs[brow  ][i*8] = bR[i];
      *(short8*)&Bs[brow+1][i*8] = bR[8+i];
    }
    __syncthreads();
    if(k0+64 < Ka) LOAD(k0+64);
#pragma unroll
    for(int kf=0;kf<2;kf++){
      short8 af[2], bf[8];
#pragma unroll
      for(int rt=0;rt<2;rt++) af[rt] = *(const short8*)&As[rt*16 + fr][kf*32 + fq];
#pragma unroll
      for(int ct=0;ct<8;ct++) bf[ct] = *(const short8*)&Bs[w*128 + ct*16 + fr][kf*32 + fq];
#pragma unroll
      for(int rt=0;rt<2;rt++)
#pragma unroll
        for(int ct=0;ct<8;ct++)
          acc[rt][ct] = __builtin_amdgcn_mfma_f32_16x16x32_bf16(af[rt], bf[ct], acc[rt][ct], 0, 0, 0);
    }
    __syncthreads();
  }

  // ---- epilogue: v = acc + bias + resid ; in-block LN over the full row ----
  float vv[2][8][4];
#pragma unroll
  for(int rt=0;rt<2;rt++){
    int ri0 = rt*16 + (ln>>4)*4;
#pragma unroll
    for(int ct=0;ct<8;ct++){
      int n = w*128 + ct*16 + fr;
      float bv = bias ? bias[n] : 0.f;
      const float* rp = resid + (size_t)(m0+ri0)*DMODEL + n;
#pragma unroll
      for(int r=0;r<4;r++)
        vv[rt][ct][r] = acc[rt][ct][r] + bv + rp[(size_t)r*DMODEL];
    }
  }

  // row sums (this wave's 128 cols): per-lane sum over 8 ct, 16-lane shfl tree
  float ps[2][4];
#pragma unroll
  for(int rt=0;rt<2;rt++)
#pragma unroll
    for(int r=0;r<4;r++){
      float s = 0.f;
#pragma unroll
      for(int ct=0;ct<8;ct++) s += vv[rt][ct][r];
      ps[rt][r] = s;
    }
#pragma unroll
  for(int off=1;off<16;off<<=1)
#pragma unroll
    for(int rt=0;rt<2;rt++)
#pragma unroll
      for(int r=0;r<4;r++) ps[rt][r] += __shfl_xor(ps[rt][r], off, 64);
  if(fr==0){
#pragma unroll
    for(int rt=0;rt<2;rt++)
#pragma unroll
      for(int r=0;r<4;r++) Ssum[rt*16 + (ln>>4)*4 + r][w] = ps[rt][r];
  }
  __syncthreads();
  if(tid<32) Smu[tid] = (Ssum[tid][0]+Ssum[tid][1]+Ssum[tid][2]+Ssum[tid][3])*(1.f/DMODEL);
  __syncthreads();

  float mu_[2][4];
#pragma unroll
  for(int rt=0;rt<2;rt++)
#pragma unroll
    for(int r=0;r<4;r++) mu_[rt][r] = Smu[rt*16 + (ln>>4)*4 + r];

#pragma unroll
  for(int rt=0;rt<2;rt++)
#pragma unroll
    for(int r=0;r<4;r++){
      float q = 0.f;
#pragma unroll
      for(int ct=0;ct<8;ct++){ float d0 = vv[rt][ct][r]-mu_[rt][r]; q += d0*d0; }
      ps[rt][r] = q;
    }
#pragma unroll
  for(int off=1;off<16;off<<=1)
#pragma unroll
    for(int rt=0;rt<2;rt++)
#pragma unroll
      for(int r=0;r<4;r++) ps[rt][r] += __shfl_xor(ps[rt][r], off, 64);
  if(fr==0){
#pragma unroll
    for(int rt=0;rt<2;rt++)
#pragma unroll
      for(int r=0;r<4;r++) Ssum[rt*16 + (ln>>4)*4 + r][w] = ps[rt][r];
  }
  __syncthreads();
  if(tid<32){
    float v2 = (Ssum[tid][0]+Ssum[tid][1]+Ssum[tid][2]+Ssum[tid][3])*(1.f/DMODEL);
    Srs[tid] = rsqrtf(v2 + LN_EPS);
  }
  __syncthreads();

#pragma unroll
  for(int rt=0;rt<2;rt++){
    int ri0 = rt*16 + (ln>>4)*4;
#pragma unroll
    for(int r=0;r<4;r++){
      int ri = ri0 + r;
      int row = m0 + ri;
      float rs = Srs[ri], mu = mu_[rt][r];
#pragma unroll
      for(int ct=0;ct<8;ct++){
        int n = w*128 + ct*16 + fr;
        float y = (vv[rt][ct][r]-mu)*rs*g[n] + bta[n];
        Yf[(size_t)row*DMODEL + n] = y;
        Yb[(size_t)row*DMODEL + n] = f2b(y);
      }
    }
  }
}

// ---------------- fused attention per (b,h); 32 rows/block; writes bf16 ---------------
__global__ __launch_bounds__(256) void attn_k(const float* __restrict__ qb,
                                              const float* __restrict__ kb,
                                              const float* __restrict__ vb,
                                              unsigned short* __restrict__ attb){
  int b = blockIdx.z, h = blockIdx.y;
  int r0 = blockIdx.x*32;
  const float* Kh = kb + (size_t)(b*NHEAD+h)*SEQ*DHEAD;
  const float* Vh = vb + (size_t)(b*NHEAD+h)*SEQ*DHEAD;
  const float* Qh = qb + (size_t)(b*NHEAD+h)*SEQ*DHEAD;
  __shared__ float kv[SEQ][DHEAD];
  __shared__ float wsm[32][132];
  __shared__ float qs[32][68];
  int tid = threadIdx.x;
  int kk = tid>>4, d4 = (tid&15)*4;

  { // K stage (xor-swizzled) + Q stage: batched float4 loads
    float4 t[8];
#pragma unroll
    for(int i=0;i<8;i++) t[i] = *(const float4*)(Kh + (size_t)(kk+16*i)*DHEAD + d4);
    float4 q0 = *(const float4*)(Qh + (size_t)(r0+kk)*DHEAD + d4);
    float4 q1 = *(const float4*)(Qh + (size_t)(r0+kk+16)*DHEAD + d4);
#pragma unroll
    for(int i=0;i<8;i++){ int k = kk+16*i; *(float4*)&kv[k][d4 ^ (k&60)] = t[i]; }
    *(float4*)&qs[kk   ][d4] = q0;
    *(float4*)&qs[kk+16][d4] = q1;
  }
  __syncthreads();

  { // logits: 2 rows x 8 keys per thread, float4 LDS reads
    int rp = tid>>4;
    int kg = tid&15;
    float acc[2][8];
#pragma unroll
    for(int i=0;i<2;i++)
#pragma unroll
      for(int kk2=0;kk2<8;kk2++) acc[i][kk2]=0.f;
#pragma unroll 4
    for(int dd=0;dd<16;dd++){
      float4 q0 = *(const float4*)&qs[2*rp][dd*4];
      float4 q1 = *(const float4*)&qs[2*rp+1][dd*4];
#pragma unroll
      for(int kk2=0;kk2<8;kk2++){
        int k = 8*kg + kk2;
        int off = (dd*4) ^ (k&60);
        float4 kv4 = *(const float4*)&kv[k][off];
        acc[0][kk2] += q0.x*kv4.x + q0.y*kv4.y + q0.z*kv4.z + q0.w*kv4.w;
        acc[1][kk2] += q1.x*kv4.x + q1.y*kv4.y + q1.z*kv4.z + q1.w*kv4.w;
      }
    }
#pragma unroll
    for(int i=0;i<2;i++){
      int t = r0 + 2*rp + i;
#pragma unroll
      for(int kk2=0;kk2<8;kk2++){
        int k = 8*kg + kk2;
        wsm[2*rp+i][k] = (k > t) ? acc[i][kk2]*0.125f : NEGF;
      }
    }
  }
  __syncthreads();

  { // softmax per row (all-masked row -> uniform 1/128, faithful to jnp)
    int l2 = tid&63, wv = tid>>6;
    for(int r=wv;r<32;r+=4){
      float l0 = wsm[r][l2], l1 = wsm[r][l2+64];
      float m = fmaxf(l0,l1);
#pragma unroll
      for(int off=32;off;off>>=1) m = fmaxf(m, __shfl_xor(m,off,64));
      float e0 = expf(l0-m), e1 = expf(l1-m);
      float s = e0+e1;
      s = wave_sum(s);
      float inv = 1.f/s;
      wsm[r][l2] = e0*inv; wsm[r][l2+64] = e1*inv;
    }
  }
  __syncthreads();

  { // V stage (overwrite kv, no swizzle): batched float4 loads
    float4 t[8];
#pragma unroll
    for(int i=0;i<8;i++) t[i] = *(const float4*)(Vh + (size_t)(kk+16*i)*DHEAD + d4);
#pragma unroll
    for(int i=0;i<8;i++) *(float4*)&kv[kk+16*i][d4] = t[i];
  }
  __syncthreads();

  { // out = w @ V, pack bf16
    int dq = (tid&15)*4, rg = tid>>4;
    for(int r=rg;r<32;r+=16){
      float4 acc2 = make_float4(0.f,0.f,0.f,0.f);
      for(int k=0;k<SEQ;k++){
        float w0 = wsm[r][k];
        float4 v = *(const float4*)&kv[k][dq];
        acc2.x += w0*v.x; acc2.y += w0*v.y; acc2.z += w0*v.z; acc2.w += w0*v.w;
      }
      int row = b*SEQ + r0 + r;
      unsigned short* op = attb + (size_t)row*DMODEL + h*DHEAD + dq;
      op[0]=f2b(acc2.x); op[1]=f2b(acc2.y); op[2]=f2b(acc2.z); op[3]=f2b(acc2.w);
    }
  }
}

// ---------------- ctx: ctxt = Wr1[:,512:]@hout[ptr-1] + cb1 (hout already LN'd) -------
__global__ __launch_bounds__(256) void ctx_k(const float* __restrict__ hout,
                                             const float* __restrict__ Wr1,
                                             const float* __restrict__ cb1,
                                             float* __restrict__ ctxt, int ptr){
  int b = blockIdx.y; int j0 = blockIdx.x*128;
  __shared__ float ctx[DMODEL];
  int tid = threadIdx.x;
  const float* rp = hout + (size_t)(b*SEQ + ptr-1)*DMODEL;
  for(int k=tid;k<DMODEL;k+=256) ctx[k]=rp[k];
  __syncthreads();
  int wv = tid>>6, l2 = tid&63;
  for(int jj=wv;jj<128;jj+=4){
    int j = j0+jj;
    const float* wp = Wr1 + (size_t)j*1024 + 512;
    float acc = 0.f;
#pragma unroll
    for(int q=0;q<8;q++){ int k = l2 + 64*q; acc += wp[k]*ctx[k]; }
    acc = wave_sum(acc);
    if(l2==0) ctxt[b*DFFN + j] = acc + cb1[j];
  }
}

// ---------------- fused refine (5 substeps) + finalize, one wg per batch --------------
__global__ __launch_bounds__(256) void refine_fin(const float* __restrict__ M1,
                                                  const float* __restrict__ ctxt,
                                                  const float* __restrict__ Wr2,
                                                  const float* __restrict__ br2,
                                                  float* __restrict__ cur_x,
                                                  const float* __restrict__ W_emb,
                                                  const float* __restrict__ b_emb,
                                                  float* __restrict__ out,
                                                  float* __restrict__ h0,
                                                  unsigned short* __restrict__ h0b,
                                                  int s, int ptr){
  int b = blockIdx.x, tid = threadIdx.x;
  __shared__ float cur[DIN], gs[DFFN], dscr[DIN];
  if(tid < DIN) cur[tid] = cur_x[b*DIN + tid];
  __syncthreads();
  for(int sub=0; sub<5; sub++){
    for(int jj=tid; jj<DFFN; jj+=256){
      float u = ctxt[b*DFFN + jj];
      const float* mp = M1 + (size_t)jj*DIN;
#pragma unroll
      for(int p=0;p<8;p++){
        float4 mv = *(const float4*)(mp + 4*p);
        u += mv.x*cur[4*p] + mv.y*cur[4*p+1] + mv.z*cur[4*p+2] + mv.w*cur[4*p+3];
      }
      gs[jj] = gelu_t(u);
    }
    __syncthreads();
    int w = tid>>6, l = tid&63;
#pragma unroll
    for(int q=0;q<8;q++){
      int i = w*8 + q;
      const float* wr = Wr2 + (size_t)i*DFFN;
      float a = 0.f;
#pragma unroll
      for(int p=0;p<8;p++){
        int j0 = p*256 + l*4;
        float4 wv = *(const float4*)(wr + j0);
        float4 gv = *(const float4*)&gs[j0];
        a += wv.x*gv.x + wv.y*gv.y + wv.z*gv.z + wv.w*gv.w;
      }
      a = wave_sum(a);
      if(l==0) dscr[i] = a;
    }
    __syncthreads();
    if(tid < DIN) cur[tid] += dscr[tid] + br2[tid];
    __syncthreads();
  }
  if(tid < DIN){
    out[(b*NSTEP + s)*DIN + tid] = cur[tid];
    cur_x[b*DIN + tid] = cur[tid];
  }
  __syncthreads();
  for(int d=tid; d<DMODEL; d+=256){
    float s2 = 0.f;
#pragma unroll 8
    for(int i=0;i<DIN;i++) s2 += W_emb[d*DIN+i]*cur[i];
    float v = SCALE_EMB*(s2 + b_emb[d]) + pe_val(ptr, d);
    size_t idx = (size_t)(b*SEQ + ptr)*DMODEL + d;
    h0[idx] = v;
    h0b[idx] = f2b(v);
  }
}

// ---------------- host ----------------
extern "C" void kernel_launch(void* const* d_in, const int* in_sizes, int n_in,
                              void* d_out, int out_size, void* d_ws, size_t ws_size,
                              hipStream_t stream) {
  (void)in_sizes; (void)n_in; (void)out_size; (void)ws_size;
  const float* hist = (const float*)d_in[0];
  const float* W_emb= (const float*)d_in[2];
  const float* b_emb= (const float*)d_in[3];
  const float* Wq   = (const float*)d_in[4];
  const float* Wk   = (const float*)d_in[5];
  const float* Wv   = (const float*)d_in[6];
  const float* Wo   = (const float*)d_in[7];
  const float* ln1g = (const float*)d_in[8];
  const float* ln1b = (const float*)d_in[9];
  const float* W1   = (const float*)d_in[10];
  const float* b1   = (const float*)d_in[11];
  const float* W2   = (const float*)d_in[12];
  const float* b2v  = (const float*)d_in[13];
  const float* ln2g = (const float*)d_in[14];
  const float* ln2b = (const float*)d_in[15];
  const float* Wr1  = (const float*)d_in[16];
  const float* br1  = (const float*)d_in[17];
  const float* Wr2  = (const float*)d_in[18];
  const float* br2  = (const float*)d_in[19];
  float* out = (float*)d_out;
  float* ws  = (float*)d_ws;

  const size_t BTD = (size_t)MROWS*DMODEL;      // 262144 floats
  const size_t BTDH = BTD/2;                    // bf16 buffer in float units
  float* h0   = ws;
  unsigned short* h0b = (unsigned short*)(h0 + BTD);
  float* hout = h0 + BTD + BTDH;                // post-LN2 stream (fp32)
  float* hlnS = hout + BTD;                     // slot reused: houtb bf16
  unsigned short* houtb = (unsigned short*)hlnS;
  float* hp   = hlnS + BTD;                     // post-LN1 stream (fp32)
  unsigned short* hpb = (unsigned short*)(hp + BTD);
  float* qb   = hp + BTD + BTDH;
  float* kb   = qb + BTD;
  float* vb   = kb + BTD;
  unsigned short* attb = (unsigned short*)(vb + BTD);
  unsigned short* fbuf16 = (unsigned short*)qb;   // [512][2048] bf16 (over qb/kb, dead then)
  unsigned short* W16 = (unsigned short*)(qb + 4*BTD);
  float* after_w = qb + 4*BTD + 6291456;
  float* M1   = after_w;
  float* cb1  = M1 + (size_t)DFFN*DIN;
  float* ctxt = cb1 + DFFN;
  float* cur_x= ctxt + NB*DFFN;

  unsigned short* Wq16 = W16;
  unsigned short* Wk16 = W16 + 1048576;
  unsigned short* Wv16 = W16 + 2097152;
  unsigned short* Wo16 = W16 + 3145728;
  unsigned short* W116 = W16 + 4194304;
  unsigned short* W216 = W16 + 8388608;

  conv_w<<<dim3(6144),dim3(256),0,stream>>>(Wq,Wk,Wv,Wo,W1,W2,W16);
  init_h0<<<dim3(MROWS),dim3(256),0,stream>>>(hist,W_emb,b_emb,h0,h0b);
  init_misc<<<dim3(256),dim3(256),0,stream>>>(Wr1,W_emb,b_emb,br1,hist,M1,cb1,cur_x);

  for(int s=0;s<NSTEP;s++){
    int ptr = TH_ + s;
    for(int l=0;l<4;l++){
      const unsigned short* Aq = (l==0)? h0b : houtb;
      const float* resW = (l==0)? h0 : hout;

      // QKV: N=1536 scatter -> qb/kb/vb
      gemm_k<<<dim3(12,8),dim3(256),0,stream>>>(Aq, DMODEL,
          Wq16 + (size_t)l*262144, Wk16 + (size_t)l*262144, Wv16 + (size_t)l*262144,
          nullptr, nullptr, qb, nullptr, 0, 2, 0);

      attn_k<<<dim3(4,NHEAD,NB),dim3(256),0,stream>>>(qb,kb,vb,attb);

      // Wo + LN1 fused: hp/hpb = LN1(att@Wo^T + resW)
      gemm_row<<<dim3(16),dim3(256),0,stream>>>(attb, DMODEL,
          Wo16 + (size_t)l*262144, nullptr, resW,
          ln1g + l*DMODEL, ln1b + l*DMODEL, hp, hpb);

      // FF1: gelu(hp@W1^T + b1) -> fbuf bf16
      gemm_k<<<dim3(16,8),dim3(256),0,stream>>>(hpb, DMODEL,
          W116 + (size_t)l*1048576, nullptr, nullptr,
          b1 + l*DFFN, nullptr, nullptr, fbuf16, DFFN, 1, 1);

      // FF2 + LN2 fused: hout/houtb = LN2(fbuf@W2^T + b2 + hp)
      gemm_row<<<dim3(16),dim3(256),0,stream>>>(fbuf16, DFFN,
          W216 + (size_t)l*1048576, b2v + l*DMODEL, hp,
          ln2g + l*DMODEL, ln2b + l*DMODEL, hout, houtb);
    }

    ctx_k<<<dim3(16,NB),dim3(256),0,stream>>>(hout, Wr1, cb1, ctxt, ptr);
    refine_fin<<<dim3(NB),dim3(256),0,stream>>>(M1, ctxt, Wr2, br2, cur_x,
                                                W_emb, b_emb, out, h0, h0b, s, ptr);
  }
}